// Round 7
// baseline (1239.285 us; speedup 1.0000x reference)
//
#include <hip/hip_runtime.h>
#include <cstdint>

static constexpr int kUsers  = 100000;
static constexpr int kItems  = 200000;
static constexpr int kNodes  = 300000;   // kUsers + kItems
static constexpr int kEmb    = 64;
static constexpr int kHops   = 3;
static constexpr int kNnz    = 2000000;
static constexpr int kStride = kHops * kEmb;   // 192 floats per node row in d_out

static constexpr int kBShift   = 6;                       // 64 rows per bucket
static constexpr int kNBuckets = (kNodes + 63) >> kBShift; // 4688
static constexpr int kNB8      = kNBuckets * 8;            // (bucket, grp) counters

#define MESS_SCALE ((float)(1.0 / 0.9))

// ---------------- threefry2x32, 20 rounds, JAX-compatible ----------------
__host__ __device__ inline void tf2x32(uint32_t k0, uint32_t k1, uint32_t& x0, uint32_t& x1) {
  uint32_t k2 = k0 ^ k1 ^ 0x1BD11BDAu;
  x0 += k0; x1 += k1;
#define TFR(r) { x0 += x1; x1 = (x1 << (r)) | (x1 >> (32 - (r))); x1 ^= x0; }
  TFR(13) TFR(15) TFR(26) TFR(6)
  x0 += k1; x1 += k2 + 1u;
  TFR(17) TFR(29) TFR(16) TFR(24)
  x0 += k2; x1 += k0 + 2u;
  TFR(13) TFR(15) TFR(26) TFR(6)
  x0 += k0; x1 += k1 + 3u;
  TFR(17) TFR(29) TFR(16) TFR(24)
  x0 += k1; x1 += k2 + 4u;
  TFR(13) TFR(15) TFR(26) TFR(6)
  x0 += k2; x1 += k0 + 5u;
#undef TFR
}

// JAX partitionable stream, 32-bit draws: threefry(key, hi=0, lo=i), word0 ^ word1
__device__ inline uint32_t draw_bits(uint32_t k0, uint32_t k1, uint32_t i) {
  uint32_t x0 = 0u, x1 = i;
  tf2x32(k0, k1, x0, x1);
  return x0 ^ x1;
}

__device__ inline float bits_to_unit(uint32_t bits) {
  return __uint_as_float((bits >> 9) | 0x3F800000u) - 1.0f;  // [0,1), JAX _uniform
}

// ======================= CSR build (bucketed, once per launch) =======================
// Record int4 {x=eid, y=val_bits, z=col, w=row (build) -> v (per hop)}

// histogram over (bucket, grp); grp = blockIdx&7 ~ XCD under round-robin dispatch
__global__ void hist2_k(const int* __restrict__ rows, int* __restrict__ cnt) {
  int e = blockIdx.x * blockDim.x + threadIdx.x;
  if (e >= kNnz) return;
  int grp = blockIdx.x & 7;
  atomicAdd(&cnt[((rows[e] >> kBShift) << 3) + grp], 1);
}

// single-block exclusive scan of cnt[kNB8] -> sub_base; bucketbase[b]=sub_base[8b];
// sentinels bucketbase[kNBuckets]=kNnz, start[kNodes]=kNnz
__global__ void scan_k(const int* __restrict__ cnt, int* __restrict__ sub_base,
                       int* __restrict__ bucketbase, int* __restrict__ start) {
  __shared__ int wsum[4];
  __shared__ int carry_s;
  int tid = threadIdx.x;
  int lane = tid & 63, wv = tid >> 6;
  if (tid == 0) carry_s = 0;
  __syncthreads();
  for (int base = 0; base < kNB8; base += 256) {
    int i = base + tid;
    int v = (i < kNB8) ? cnt[i] : 0;
    int x = v;
    for (int off = 1; off < 64; off <<= 1) {
      int y = __shfl_up(x, off);
      if (lane >= off) x += y;
    }
    if (lane == 63) wsum[wv] = x;
    __syncthreads();
    int woff = 0;
    if (wv >= 1) woff += wsum[0];
    if (wv >= 2) woff += wsum[1];
    if (wv >= 3) woff += wsum[2];
    int excl = carry_s + woff + (x - v);
    if (i < kNB8) sub_base[i] = excl;
    __syncthreads();
    if (tid == 0) carry_s += wsum[0] + wsum[1] + wsum[2] + wsum[3];
    __syncthreads();
  }
  for (int b = tid; b < kNBuckets; b += 256) bucketbase[b] = sub_base[b << 3];
  if (tid == 0) { bucketbase[kNBuckets] = kNnz; start[kNodes] = kNnz; }
}

// scatter edges to their (bucket,grp) sub-region; frontier lines are L2-resident and
// single-XCD (grp) -> full-line evictions
__global__ void phase1_k(const int* __restrict__ rows, const int* __restrict__ cols,
                         const float* __restrict__ vals,
                         const int* __restrict__ sub_base, int* __restrict__ bcur,
                         int4* __restrict__ pv) {
  int e = blockIdx.x * blockDim.x + threadIdx.x;
  if (e >= kNnz) return;
  int grp = blockIdx.x & 7;
  int r = rows[e];
  int slot = ((r >> kBShift) << 3) + grp;
  int p = sub_base[slot] + atomicAdd(&bcur[slot], 1);
  pv[p] = make_int4(e, __float_as_int(vals[e]), cols[e], r);
}

// one block per bucket: in-place sort into exact row order; emit exact CSR start[]
__global__ void phase2_k(const int* __restrict__ bucketbase, int4* __restrict__ pv,
                         int* __restrict__ start) {
  constexpr int LCAP = 2048;  // LDS record cap
  constexpr int RPT  = 8;     // +2048 in registers (unreachable headroom)
  __shared__ int4 sbuf[LCAP];
  __shared__ int rcnt[64];
  __shared__ int rcur[64];
  int tid = threadIdx.x;
  int b = blockIdx.x;
  int base = bucketbase[b], end = bucketbase[b + 1];
  int n = end - base;
  int r0 = b << kBShift;
  if (tid < 64) rcnt[tid] = 0;
  __syncthreads();
  int4 rreg[RPT];
  for (int i = tid; i < n && i < LCAP; i += 256) {
    int4 rec = pv[base + i];
    sbuf[i] = rec;
    atomicAdd(&rcnt[rec.w - r0], 1);
  }
#pragma unroll
  for (int j = 0; j < RPT; ++j) {
    int i = LCAP + j * 256 + tid;
    if (i < n) {
      int4 rec = pv[base + i];
      rreg[j] = rec;
      atomicAdd(&rcnt[rec.w - r0], 1);
    }
  }
  __syncthreads();
  if (tid < 64) {
    int v = rcnt[tid];
    int x = v;
    for (int off = 1; off < 64; off <<= 1) {
      int y = __shfl_up(x, off);
      if (tid >= off) x += y;
    }
    int excl = x - v;
    rcur[tid] = base + excl;
    int r = r0 + tid;
    if (r < kNodes) start[r] = base + excl;   // exact CSR row start
  }
  __syncthreads();
  for (int i = tid; i < n && i < LCAP; i += 256) {
    int4 rec = sbuf[i];
    int dst = atomicAdd(&rcur[rec.w - r0], 1);
    pv[dst] = rec;
  }
#pragma unroll
  for (int j = 0; j < RPT; ++j) {
    int i = LCAP + j * 256 + tid;
    if (i < n) {
      int4 rec = rreg[j];
      int dst = atomicAdd(&rcur[rec.w - r0], 1);
      pv[dst] = rec;
    }
  }
}

// ======================= per-hop kernels =======================

// write this hop's dropped+rescaled value into pv[p].w; RNG keyed by ORIGINAL edge id
__global__ void edge_vals_csr_k(int4* __restrict__ pv, uint32_t ek0, uint32_t ek1) {
  int p = blockIdx.x * blockDim.x + threadIdx.x;
  if (p >= kNnz) return;
  int2 ev = ((const int2*)pv)[2 * p];   // {eid, val_bits}, 8B aligned
  uint32_t bits = draw_bits(ek0, ek1, (uint32_t)ev.x);
  // keep iff floor(0.5+u) > 0 <=> u >= 0.5 <=> top bit set (exact: u = k*2^-23)
  float v = (bits & 0x80000000u) ? __int_as_float(ev.y) * 2.0f : 0.0f;
  ((int*)pv)[4 * p + 3] = __float_as_int(v);
}

// one wave per row, lane = emb dim. 8-wide unrolled, branch-free gather loop; hot-loop
// edge loads are 8B int2 {col, v}. Dropped/dup slots redirect to the row's first source
// row (L1-hot line) and contribute exactly 0.
template <bool HOP0>
__global__ __launch_bounds__(256, 4) void row_gather_k(
    const int* __restrict__ start, const int* __restrict__ endp,
    const int4* __restrict__ pv,
    const float* __restrict__ ue, const float* __restrict__ ie,
    const float* __restrict__ prev,   // hop>=1 source slice
    float* __restrict__ out, uint32_t mk0, uint32_t mk1, int hop) {
  int wid = (int)(((long long)blockIdx.x * blockDim.x + threadIdx.x) >> 6);  // row
  int d = threadIdx.x & 63;
  if (wid >= kNodes) return;
  int s = start[wid];
  int e = endp[wid];   // == start[wid+1]
  float acc = 0.0f;
  const float* isft = ie - (long long)kUsers * kEmb;  // item base shifted by user count
  const int2* pvh = (const int2*)pv;                  // pvh[2p+1] = {col, v}
  if (e > s) {
    int c0 = pvh[2 * s + 1].x;   // redirect target for dropped/dup slots (hot line)
    for (int k = s; k < e; k += 8) {
#pragma unroll
      for (int j = 0; j < 8; ++j) {
        int kk = k + j;
        bool live = kk < e;
        int idx = live ? kk : s;
        int2 cv = pvh[2 * idx + 1];
        float v = live ? __int_as_float(cv.y) : 0.0f;
        int c = (v != 0.0f) ? cv.x : c0;
        float x;
        if (HOP0) {
          const float* bp = (c < kUsers) ? ue : isft;
          x = bp[(long long)c * kEmb + d];
        } else {
          x = prev[(long long)c * kStride + d];
        }
        acc += v * x;   // v==0 slots: 0 * (valid finite float) == 0, bit-exact
      }
    }
  }
  // message dropout on agg[wid, d]: flat index over (kNodes, kEmb)
  uint32_t bits = draw_bits(mk0, mk1, (uint32_t)(wid * kEmb + d));
  float u = bits_to_unit(bits);
  float res = (u >= 0.1f) ? acc * MESS_SCALE : 0.0f;
  out[(long long)wid * kStride + hop * kEmb + d] = res;
}

// ================= fallback path (round-2 proven; used if ws too small) =================

__global__ void edge_vals_k(const float* __restrict__ adj_vals, float* __restrict__ v_out,
                            uint32_t ek0, uint32_t ek1) {
  int e = blockIdx.x * blockDim.x + threadIdx.x;
  if (e >= kNnz) return;
  uint32_t bits = draw_bits(ek0, ek1, (uint32_t)e);
  v_out[e] = (bits & 0x80000000u) ? adj_vals[e] * 2.0f : 0.0f;
}

__global__ void scatter_k(const int* __restrict__ rows, const int* __restrict__ cols,
                          const float* __restrict__ vvals,
                          const float* __restrict__ user_emb, const float* __restrict__ item_emb,
                          const float* __restrict__ prev, float* __restrict__ acc) {
  long long t = (long long)blockIdx.x * blockDim.x + threadIdx.x;
  int e = (int)(t >> 6);
  int d = (int)(t & 63);
  if (e >= kNnz) return;
  float ve = vvals[e];
  if (ve == 0.0f) return;
  int c = cols[e];
  int r = rows[e];
  float x;
  if (prev) x = prev[(long long)c * kStride + d];
  else x = (c < kUsers) ? user_emb[(long long)c * kEmb + d]
                        : item_emb[(long long)(c - kUsers) * kEmb + d];
  unsafeAtomicAdd(&acc[(long long)r * kStride + d], ve * x);
}

__global__ void mess_k(float* __restrict__ slice, uint32_t mk0, uint32_t mk1) {
  long long i = (long long)blockIdx.x * blockDim.x + threadIdx.x;
  const long long total = (long long)kNodes * kEmb;
  if (i >= total) return;
  uint32_t bits = draw_bits(mk0, mk1, (uint32_t)i);
  float u = bits_to_unit(bits);
  int n = (int)(i >> 6), d = (int)(i & 63);
  long long idx = (long long)n * kStride + d;
  float val = slice[idx];
  slice[idx] = (u >= 0.1f) ? val * MESS_SCALE : 0.0f;
}

// ================= launch =================

extern "C" void kernel_launch(void* const* d_in, const int* in_sizes, int n_in,
                              void* d_out, int out_size, void* d_ws, size_t ws_size,
                              hipStream_t stream) {
  const float* user_emb = (const float*)d_in[0];
  const float* item_emb = (const float*)d_in[1];
  const float* adj_vals = (const float*)d_in[2];
  const int*   adj_rows = (const int*)d_in[3];
  const int*   adj_cols = (const int*)d_in[4];
  float* out = (float*)d_out;

  // ws layout (bytes; 128B-aligned chunks, pv 16B-aligned)
  char* base = (char*)d_ws;
  const size_t off_start = 0;          // (kNodes+1) ints = 1,200,004 -> 1,200,128
  const size_t off_cnt   = 1200128;    // kNB8 ints = 150,016
  const size_t off_sub   = 1350144;    // kNB8 ints
  const size_t off_bcur  = 1500160;    // kNB8 ints
  const size_t off_bbase = 1650176;    // (kNBuckets+1) ints = 18,756 -> 18,944
  const size_t off_pv    = 1669120;    // kNnz int4 = 32,000,000
  const size_t needed    = 33669120;

  uint32_t ek0[kHops], ek1[kHops], mk0[kHops], mk1[kHops];
  for (int hop = 0; hop < kHops; ++hop) {
    ek0[hop] = 0u; ek1[hop] = (uint32_t)(2 * hop);
    tf2x32(0u, 42u, ek0[hop], ek1[hop]);   // fold_in(key(42), 2h)
    mk0[hop] = 0u; mk1[hop] = (uint32_t)(2 * hop + 1);
    tf2x32(0u, 42u, mk0[hop], mk1[hop]);   // fold_in(key(42), 2h+1)
  }

  if (ws_size >= needed) {
    int*  start = (int*)(base + off_start);
    int*  cnt   = (int*)(base + off_cnt);
    int*  subb  = (int*)(base + off_sub);
    int*  bcur  = (int*)(base + off_bcur);
    int*  bbase = (int*)(base + off_bbase);
    int4* pv    = (int4*)(base + off_pv);

    hipMemsetAsync(cnt, 0, (size_t)kNB8 * sizeof(int), stream);
    hipMemsetAsync(bcur, 0, (size_t)kNB8 * sizeof(int), stream);

    const int egrid = (kNnz + 255) / 256;
    hist2_k<<<egrid, 256, 0, stream>>>(adj_rows, cnt);
    scan_k<<<1, 256, 0, stream>>>(cnt, subb, bbase, start);
    phase1_k<<<egrid, 256, 0, stream>>>(adj_rows, adj_cols, adj_vals, subb, bcur, pv);
    phase2_k<<<kNBuckets, 256, 0, stream>>>(bbase, pv, start);

    long long nthreads = (long long)kNodes * 64;
    int ngrid = (int)((nthreads + 255) / 256);
    for (int hop = 0; hop < kHops; ++hop) {
      edge_vals_csr_k<<<egrid, 256, 0, stream>>>(pv, ek0[hop], ek1[hop]);
      if (hop == 0) {
        row_gather_k<true><<<ngrid, 256, 0, stream>>>(
            start, start + 1, pv, user_emb, item_emb, nullptr, out, mk0[hop], mk1[hop], hop);
      } else {
        const float* prev = out + (long long)(hop - 1) * kEmb;
        row_gather_k<false><<<ngrid, 256, 0, stream>>>(
            start, start + 1, pv, user_emb, item_emb, prev, out, mk0[hop], mk1[hop], hop);
      }
    }
  } else {
    // fallback: round-2 scatter path (needs only kNnz floats of ws)
    float* vbuf = (float*)d_ws;
    hipMemsetAsync(d_out, 0, (size_t)out_size * sizeof(float), stream);
    for (int hop = 0; hop < kHops; ++hop) {
      edge_vals_k<<<(kNnz + 255) / 256, 256, 0, stream>>>(adj_vals, vbuf, ek0[hop], ek1[hop]);
      const float* prev = (hop == 0) ? nullptr : (out + (long long)(hop - 1) * kEmb);
      float* acc = out + (long long)hop * kEmb;
      long long nthreads = (long long)kNnz * 64;
      scatter_k<<<(int)((nthreads + 255) / 256), 256, 0, stream>>>(
          adj_rows, adj_cols, vbuf, user_emb, item_emb, prev, acc);
      long long etotal = (long long)kNodes * kEmb;
      mess_k<<<(int)((etotal + 255) / 256), 256, 0, stream>>>(acc, mk0[hop], mk1[hop]);
    }
  }
}